// Round 9
// baseline (52.918 us; speedup 1.0000x reference)
//
#include <hip/hip_runtime.h>
#include <math.h>

// out[b,i,h,w] = Ar[b,h,i]*cos(2*pi*i*w/128)/128 - Ai[b,h,i]*sin(2*pi*i*w/128)/128
// A = row-DFT of x (fft2 + ifft over H == fft over W). mask unused.
//
// v8: LINEAR WRITE MAP. No mirror planes (DFT is cheap & hideable; symmetry
// only saved compute, not bytes): block (b,q) computes planes {4q..4q+3}
// directly and writes ONE contiguous 256 KB region. Bijective XCD swizzle
// (hw round-robins blockIdx across 8 XCDs) gives each XCD a contiguous
// 32 MB write slab and keeps all 32 blocks reading a given b's x-slab on
// one XCD's L2. Zero LDS, zero barriers, register-resident x, plane DFT
// software-pipelined behind the previous plane's in-flight stores (v6).
// Grid: 1024 = 32 b x 32 quad-groups.

typedef float f32x4 __attribute__((ext_vector_type(4)));

__device__ __forceinline__ void rot_step(float& cr, float& ci, float dc, float ds) {
    const float ncr = fmaf(cr, dc, -ci * ds);
    ci = fmaf(cr, ds, ci * dc);
    cr = ncr;
}

__device__ __forceinline__ void dft_full(const float* xs, int i, int half,
                                         float& arO, float& aiO) {
    // e^{-I*2*pi*i/128} rotation; phase re-anchored exactly every 32 steps
    float ss, cs;
    sincospif((float)i * (1.0f / 64.0f), &ss, &cs);
    const float dc = cs, ds = -ss;
    float ar = 0.0f, ai = 0.0f;
#pragma unroll
    for (int ch = 0; ch < 2; ++ch) {
        const int u0 = half * 64 + ch * 32;
        float s0, c0;
        sincospif((float)((i * u0) & 127) * (1.0f / 64.0f), &s0, &c0);
        float cr = c0, ci = -s0;
#pragma unroll
        for (int j = 0; j < 32; ++j) {
            const float xv = xs[ch * 32 + j];
            ar = fmaf(xv, cr, ar);
            ai = fmaf(xv, ci, ai);
            rot_step(cr, ci, dc, ds);
        }
    }
    ar += __shfl_xor(ar, 1);   // pair combine: both lanes hold the full sum
    ai += __shfl_xor(ai, 1);
    arO = ar * (1.0f / 128.0f);
    aiO = ai * (1.0f / 128.0f);
}

__global__ __launch_bounds__(256) void kspace_v8(const float* __restrict__ x,
                                                 float* __restrict__ out) {
    // bijective XCD swizzle: XCD k (= blockIdx%8) handles contiguous wgids
    const int blk  = blockIdx.x;            // 0..1023
    const int wgid = (blk & 7) * 128 + (blk >> 3);
    const int b    = wgid >> 5;
    const int q    = wgid & 31;             // quad-group: planes 4q..4q+3
    const int t    = threadIdx.x;
    const int wv   = t >> 6;                // wave 0..3 -> rows [32wv,32wv+32)
    const int lane = t & 63;
    const int h    = wv * 32 + (lane >> 1); // this thread's DFT row
    const int half = lane & 1;              // which 64-sample half

    // ---- my half-row (64 floats, 256 B contiguous) into registers ----
    const float* xp = x + ((size_t)b * 128 + h) * 128 + half * 64;
    float xs[64];
#pragma unroll
    for (int j = 0; j < 16; ++j) {
        const f32x4 v = ((const f32x4*)xp)[j];
        xs[4 * j + 0] = v.x;
        xs[4 * j + 1] = v.y;
        xs[4 * j + 2] = v.z;
        xs[4 * j + 3] = v.w;
    }

    // peel DFT of first plane
    float arC, aiC;
    dft_full(xs, 4 * q, half, arC, aiC);

    const int wbase = (lane & 31) * 4;      // this lane's 4 w-columns

#pragma unroll
    for (int pp = 0; pp < 4; ++pp) {
        const int i = 4 * q + pp;

        // per-lane trig for its 4 fixed w-columns (exact mod-128 phases)
        float cwv[4], swv[4];
#pragma unroll
        for (int c = 0; c < 4; ++c) {
            const int k = (i * (wbase + c)) & 127;
            sincospif((float)k * (1.0f / 64.0f), &swv[c], &cwv[c]);
        }

        // store plane i: wave wv writes f32x4 q4 = wv*1024 + 64j + lane
        // (1 KB/instr, coalesced); row = 32wv + 2j + (lane>>5);
        // A owner lane = 4j + 2*(lane>>5)
        f32x4* const o = (f32x4*)out + (size_t)(b * 128 + i) * 4096;
#pragma unroll
        for (int j = 0; j < 16; ++j) {
            const int src = 4 * j + 2 * (lane >> 5);
            const float a  = __shfl(arC, src);
            const float bb = __shfl(aiC, src);
            f32x4 v;
            v.x = fmaf(a, cwv[0], -bb * swv[0]);
            v.y = fmaf(a, cwv[1], -bb * swv[1]);
            v.z = fmaf(a, cwv[2], -bb * swv[2]);
            v.w = fmaf(a, cwv[3], -bb * swv[3]);
            o[wv * 1024 + j * 64 + lane] = v;
        }

        // next plane's DFT overlaps the in-flight stores above
        if (pp < 3) {
            dft_full(xs, i + 1, half, arC, aiC);
        }
    }
}

extern "C" void kernel_launch(void* const* d_in, const int* in_sizes, int n_in,
                              void* d_out, int out_size, void* d_ws, size_t ws_size,
                              hipStream_t stream) {
    const float* x = (const float*)d_in[0];   // (32,1,128,128) f32; mask unused
    float* out = (float*)d_out;               // (32,128,128,128) f32
    kspace_v8<<<dim3(1024), dim3(256), 0, stream>>>(x, out);
}